// Round 13
// baseline (84.907 us; speedup 1.0000x reference)
//
#include <hip/hip_runtime.h>

#define BB 16
#define HIMG 64
#define WIMG 64
#define CC 256
#define NHEAD 8
#define HD 32
#define NN 4096
#define PWD 65   // 2*DH+1
#define PADC 264 // qr_bf row stride (ushorts)
#define NCH 32   // k1 chunks per batch (128 rows each)
#define TSTR 72  // transpose-LDS row stride (ushorts): 144B = 16B-aligned b128 reads

typedef short bf16x8 __attribute__((ext_vector_type(8)));
typedef float f32x4 __attribute__((ext_vector_type(4)));

__device__ __forceinline__ float elu1(float x) {
    return x > 0.0f ? x + 1.0f : __expf(x);
}
__device__ __forceinline__ float sigm(float x) {
    return 1.0f / (1.0f + __expf(-x));
}
__device__ __forceinline__ unsigned short f2bf(float f) {
    union { float f; unsigned int u; } v; v.f = f;
    unsigned int r = v.u + 0x7FFFu + ((v.u >> 16) & 1u);   // RNE
    return (unsigned short)(r >> 16);
}

// ---------------- Kernel 0: pw[n][c] = sigmoid(posw[i+1][j+1][c]) ---------------
__global__ __launch_bounds__(256) void k0_pw(
    const float* __restrict__ posw, float* __restrict__ pw)
{
    const int gid = blockIdx.x * 256 + threadIdx.x;  // 0 .. 262143
    const int n = gid >> 6;
    const int p = gid & 63;
    const int ii = n >> 6, jj = n & 63;
    const float4 v = *(const float4*)(posw + (size_t)((ii + 1) * PWD + (jj + 1)) * CC + p * 4);
    float4 r;
    r.x = sigm(v.x); r.y = sigm(v.y); r.z = sigm(v.z); r.w = sigm(v.w);
    *(float4*)(pw + (size_t)n * CC + p * 4) = r;
}

// ---------------- Kernel 1: partial kv via wave-private MFMA, no barriers -------
// grid = 2048 x 128 (2 waves). Wave -> (b, head, 128-row chunk). Small blocks +
// 18KiB LDS -> 8 blocks/CU = 16 waves/CU (occupancy was the R12 limiter).
// Per 64-row slab: 24 coalesced float4 loads, elu+gate -> bf16, transpose-stage
// to wave-private LDS [d][n]/[e][n] (stride 72 -> aligned b128 fragment reads),
// 8x mfma_16x16x32_bf16. ksum exact f32 + shfl reduce. Zero __syncthreads.
__global__ __launch_bounds__(128, 4) void k1_partial(
    const float* __restrict__ x2, const float* __restrict__ x3,
    const float* __restrict__ pw, float* __restrict__ pkv,
    float* __restrict__ pksum)
{
    __shared__ unsigned short krT[2][HD][TSTR];   // 9.2 KiB
    __shared__ unsigned short vT[2][HD][TSTR];    // 9.2 KiB

    const int t     = threadIdx.x;
    const int wv    = t >> 6;                // 0..1
    const int gw    = blockIdx.x * 2 + wv;   // 0..4095
    const int b     = gw >> 8;
    const int rem   = gw & 255;
    const int h     = rem >> 5;
    const int chunk = rem & 31;
    const int n0    = chunk * 128;
    const int l     = t & 63;
    const int r8    = l >> 3;      // row-within-8
    const int cq    = l & 7;       // channel quad

    const float* x2b = x2 + (size_t)b * NN * CC + h * HD + cq * 4;
    const float* x3b = x3 + (size_t)b * NN * CC + h * HD + cq * 4;
    const float* pwb = pw + h * HD + cq * 4;

    f32x4 a00 = {0.f,0.f,0.f,0.f}, a01 = {0.f,0.f,0.f,0.f};
    f32x4 a10 = {0.f,0.f,0.f,0.f}, a11 = {0.f,0.f,0.f,0.f};
    float ks0 = 0.f, ks1 = 0.f, ks2 = 0.f, ks3 = 0.f;

    float4 kx[8], pv[8], vx[8];

#define K1_ISSUE(sl)                                                          \
    do {                                                                      \
        _Pragma("unroll")                                                     \
        for (int i = 0; i < 8; ++i) {                                         \
            const size_t n_ = (size_t)(n0 + (sl) * 64 + i * 8 + r8) * CC;     \
            kx[i] = *(const float4*)(x2b + n_);                               \
        }                                                                     \
        _Pragma("unroll")                                                     \
        for (int i = 0; i < 8; ++i) {                                         \
            const size_t n_ = (size_t)(n0 + (sl) * 64 + i * 8 + r8) * CC;     \
            pv[i] = *(const float4*)(pwb + n_);                               \
        }                                                                     \
        _Pragma("unroll")                                                     \
        for (int i = 0; i < 8; ++i) {                                         \
            const size_t n_ = (size_t)(n0 + (sl) * 64 + i * 8 + r8) * CC;     \
            vx[i] = *(const float4*)(x3b + n_);                               \
        }                                                                     \
    } while (0)

#define K1_SLAB(PREF)                                                         \
    do {                                                                      \
        _Pragma("unroll")                                                     \
        for (int i = 0; i < 8; ++i) {                                         \
            const int nl = i * 8 + r8;                                        \
            const float e0 = elu1(kx[i].x), e1 = elu1(kx[i].y);               \
            const float e2 = elu1(kx[i].z), e3 = elu1(kx[i].w);               \
            ks0 += e0; ks1 += e1; ks2 += e2; ks3 += e3;                       \
            krT[wv][cq * 4 + 0][nl] = f2bf(e0 * pv[i].x);                     \
            krT[wv][cq * 4 + 1][nl] = f2bf(e1 * pv[i].y);                     \
            krT[wv][cq * 4 + 2][nl] = f2bf(e2 * pv[i].z);                     \
            krT[wv][cq * 4 + 3][nl] = f2bf(e3 * pv[i].w);                     \
            vT[wv][cq * 4 + 0][nl] = f2bf(vx[i].x);                           \
            vT[wv][cq * 4 + 1][nl] = f2bf(vx[i].y);                           \
            vT[wv][cq * 4 + 2][nl] = f2bf(vx[i].z);                           \
            vT[wv][cq * 4 + 3][nl] = f2bf(vx[i].w);                           \
        }                                                                     \
        if (PREF) K1_ISSUE(1);                                                \
        _Pragma("unroll")                                                     \
        for (int kc = 0; kc < 2; ++kc) {                                      \
            const int ko = kc * 32 + (l >> 4) * 8;                            \
            const bf16x8 fa0 = *(const bf16x8*)&krT[wv][l & 15][ko];          \
            const bf16x8 fa1 = *(const bf16x8*)&krT[wv][16 + (l & 15)][ko];   \
            const bf16x8 fb0 = *(const bf16x8*)&vT[wv][l & 15][ko];           \
            const bf16x8 fb1 = *(const bf16x8*)&vT[wv][16 + (l & 15)][ko];    \
            a00 = __builtin_amdgcn_mfma_f32_16x16x32_bf16(fa0, fb0, a00, 0, 0, 0); \
            a01 = __builtin_amdgcn_mfma_f32_16x16x32_bf16(fa0, fb1, a01, 0, 0, 0); \
            a10 = __builtin_amdgcn_mfma_f32_16x16x32_bf16(fa1, fb0, a10, 0, 0, 0); \
            a11 = __builtin_amdgcn_mfma_f32_16x16x32_bf16(fa1, fb1, a11, 0, 0, 0); \
        }                                                                     \
    } while (0)

    K1_ISSUE(0);
    K1_SLAB(1);     // slab 0; prefetch slab 1 between convert and MFMA
    K1_SLAB(0);     // slab 1

#undef K1_ISSUE
#undef K1_SLAB

    // ---- store kv partial in MFMA-native layout: o = h*1024 + tile*256 + l*4+reg
    float* dst = pkv + (size_t)(b * NCH + chunk) * (NHEAD * HD * HD) + h * (HD * HD);
    *(f32x4*)(dst + 0 * 256 + l * 4) = a00;   // tile (dt=0,et=0)
    *(f32x4*)(dst + 1 * 256 + l * 4) = a01;   // tile (dt=0,et=1)
    *(f32x4*)(dst + 2 * 256 + l * 4) = a10;   // tile (dt=1,et=0)
    *(f32x4*)(dst + 3 * 256 + l * 4) = a11;   // tile (dt=1,et=1)

    // ---- ksum: reduce over row-lanes (l bits 3..5), lanes 0..7 hold channel quads
    ks0 += __shfl_xor(ks0, 8);  ks1 += __shfl_xor(ks1, 8);
    ks2 += __shfl_xor(ks2, 8);  ks3 += __shfl_xor(ks3, 8);
    ks0 += __shfl_xor(ks0, 16); ks1 += __shfl_xor(ks1, 16);
    ks2 += __shfl_xor(ks2, 16); ks3 += __shfl_xor(ks3, 16);
    ks0 += __shfl_xor(ks0, 32); ks1 += __shfl_xor(ks1, 32);
    ks2 += __shfl_xor(ks2, 32); ks3 += __shfl_xor(ks3, 32);
    if (l < 8) {
        float4 o4 = {ks0, ks1, ks2, ks3};
        *(float4*)(pksum + (size_t)(b * NCH + chunk) * CC + h * HD + l * 4) = o4;
    }
}

// ---------------- Kernel 2: reduce partials; emit kvbT (bf16, [b][h][e][d]) -----
// grid = 512, block = 256. pkv o-layout is MFMA-native: h*1024 + tile*256 + l*4+r.
__global__ __launch_bounds__(256) void k2_reduce(
    const float* __restrict__ pkv, const float* __restrict__ pksum,
    unsigned short* __restrict__ kvbT, float* __restrict__ kmean)
{
    const int gid = blockIdx.x * 256 + threadIdx.x;   // over B*8192
    const int b = gid >> 13;
    const int o = gid & 8191;
    float s = 0.f;
#pragma unroll 4
    for (int c = 0; c < NCH; ++c)
        s += pkv[(size_t)(b * NCH + c) * (NHEAD * HD * HD) + o];
    const int hh   = o >> 10;
    const int r1   = o & 1023;
    const int tile = r1 >> 8;
    const int li   = (r1 >> 2) & 63;
    const int rg   = o & 3;
    const int d    = (tile >> 1) * 16 + (li >> 4) * 4 + rg;
    const int e    = (tile & 1) * 16 + (li & 15);
    kvbT[(((size_t)b * NHEAD + hh) * HD + e) * HD + d] = f2bf(s * (1.0f / NN));
    if (o < CC) {
        float ss = 0.f;
#pragma unroll 4
        for (int c = 0; c < NCH; ++c)
            ss += pksum[(size_t)(b * NCH + c) * CC + o];
        kmean[b * CC + o] = ss * (1.0f / NN);
    }
}

// ---------------- Kernel 3: out = MFMA((qr*z) @ kv) + LePE ----------------------
// grid = B*256 (quarter image row each), block = 256 (4 waves)
__global__ __launch_bounds__(256, 2) void k3_out(
    const float* __restrict__ x1, const float* __restrict__ x3,
    const float* __restrict__ pw, const unsigned short* __restrict__ kvbT,
    const float* __restrict__ kmean, const float* __restrict__ lw,
    const float* __restrict__ lb, float* __restrict__ out)
{
    const int blk  = blockIdx.x;      // b*256 + irow*4 + jq
    const int b    = blk >> 8;
    const int irow = (blk >> 2) & 63;
    const int jq   = blk & 3;
    const int j0   = jq << 4;         // 0, 16, 32, 48
    const int t    = threadIdx.x;

    __shared__ unsigned short qr_bf[16 * PADC];   // (qr * z) in bf16, 8.4 KiB
    __shared__ float attn_lds[16][CC];            // 16 KiB

    float wreg[9];
#pragma unroll
    for (int q = 0; q < 9; ++q) wreg[q] = lw[t * 9 + q];
    const float bias = lb[t];

    // ---- stage: q_rope * z  -> bf16 LDS (z folded in; known after shfl reduce) ----
    {
        const int p    = t & 63;       // float4 slot within a pixel's 256 channels
        const int pixo = t >> 6;       // 0..3
        const float4 km4 = *(const float4*)(kmean + b * CC + p * 4);
        const float* x1b = x1 + ((size_t)b * NN + (size_t)irow * 64 + j0) * CC;
        const float* pwb = pw + ((size_t)irow * 64 + j0) * CC;
        float4 xv[4], pvv[4];
#pragma unroll
        for (int s = 0; s < 4; ++s)
            xv[s] = *(const float4*)(x1b + (size_t)(s * 4 + pixo) * CC + p * 4);
#pragma unroll
        for (int s = 0; s < 4; ++s)
            pvv[s] = *(const float4*)(pwb + (size_t)(s * 4 + pixo) * CC + p * 4);
#pragma unroll
        for (int s = 0; s < 4; ++s) {
            const int pix = s * 4 + pixo;   // 0..15 (local)
            float4 q4;
            q4.x = elu1(xv[s].x); q4.y = elu1(xv[s].y);
            q4.z = elu1(xv[s].z); q4.w = elu1(xv[s].w);
            float zp = q4.x * km4.x + q4.y * km4.y + q4.z * km4.z + q4.w * km4.w;
            zp += __shfl_xor(zp, 1);
            zp += __shfl_xor(zp, 2);
            zp += __shfl_xor(zp, 4);        // all 8 lanes of this head have the sum
            const float zin = 1.0f / (zp + 1e-6f);
            ushort4 u;
            u.x = f2bf(q4.x * pvv[s].x * zin);
            u.y = f2bf(q4.y * pvv[s].y * zin);
            u.z = f2bf(q4.z * pvv[s].z * zin);
            u.w = f2bf(q4.w * pvv[s].w * zin);
            *(ushort4*)(&qr_bf[pix * PADC + p * 4]) = u;
        }
    }

    // ---- halo loads issued BEFORE the barrier: cannot be sunk past it ----
    const bool hasU = irow > 0, hasD = irow < 63;
    const float* rU = x3 + ((size_t)b * NN + (size_t)(irow - 1) * 64 + j0) * CC + t;
    const float* rM = x3 + ((size_t)b * NN + (size_t)irow * 64 + j0) * CC + t;
    const float* rD = x3 + ((size_t)b * NN + (size_t)(irow + 1) * 64 + j0) * CC + t;

    float cu[2][10], cm[2][10], cd[2][10];
#pragma unroll
    for (int tt = 0; tt < 2; ++tt)
#pragma unroll
        for (int q = 0; q < 10; ++q) {
            const int col = tt * 8 + q - 1;     // local col in [-1, 16]
            const int g   = j0 + col;           // global col in [-1, 64]
            const bool ok = (g >= 0) && (g < 64);
            const long off = (long)col * CC;
            cm[tt][q] = ok ? rM[off] : 0.f;
            cu[tt][q] = (ok && hasU) ? rU[off] : 0.f;
            cd[tt][q] = (ok && hasD) ? rD[off] : 0.f;
        }

    __syncthreads();

    // ---- MFMA phase: wave w covers heads 2w,2w+1 over all 16 pixels ----
    {
        const int w  = t >> 6;
        const int l  = t & 63;
        const int lr = l & 15;     // A row (pixel) / B col / D col
        const int lg = l >> 4;     // k-group

        bf16x8 af0 = *(const bf16x8*)(&qr_bf[lr * PADC + (w * 2 + 0) * HD + lg * 8]);
        bf16x8 af1 = *(const bf16x8*)(&qr_bf[lr * PADC + (w * 2 + 1) * HD + lg * 8]);

        f32x4 acc[4];
#pragma unroll
        for (int ct = 0; ct < 4; ++ct) {
            const int head = w * 2 + (ct >> 1);
            const int cl   = (ct & 1) * 16 + lr;
            const bf16x8 bf = *(const bf16x8*)(kvbT +
                (((size_t)b * NHEAD + head) * HD + cl) * HD + lg * 8);
            f32x4 z4 = {0.f, 0.f, 0.f, 0.f};
            acc[ct] = __builtin_amdgcn_mfma_f32_16x16x32_bf16(
                (ct < 2) ? af0 : af1, bf, z4, 0, 0, 0);
        }
#pragma unroll
        for (int ct = 0; ct < 4; ++ct) {
            const int c = (w * 2 + (ct >> 1)) * HD + (ct & 1) * 16 + lr;
#pragma unroll
            for (int r = 0; r < 4; ++r)
                attn_lds[lg * 4 + r][c] = acc[ct][r];
        }
    }

    __syncthreads();

    // ---- epilogue: lepe (registers already loaded) + attn + store ----
    float* ob = out + ((size_t)b * NN + (size_t)irow * 64 + j0) * CC + t;
#pragma unroll
    for (int tt = 0; tt < 2; ++tt) {
#pragma unroll
        for (int q = 0; q < 8; ++q) {
            const int jl = tt * 8 + q;          // local pixel 0..15
            float lepe = bias
                + wreg[0] * cu[tt][q] + wreg[1] * cu[tt][q + 1] + wreg[2] * cu[tt][q + 2]
                + wreg[3] * cm[tt][q] + wreg[4] * cm[tt][q + 1] + wreg[5] * cm[tt][q + 2]
                + wreg[6] * cd[tt][q] + wreg[7] * cd[tt][q + 1] + wreg[8] * cd[tt][q + 2];
            __builtin_nontemporal_store(attn_lds[jl][t] + lepe, ob + (long)jl * CC);
        }
    }
}

extern "C" void kernel_launch(void* const* d_in, const int* in_sizes, int n_in,
                              void* d_out, int out_size, void* d_ws, size_t ws_size,
                              hipStream_t stream) {
    const float* x1   = (const float*)d_in[0];
    const float* x2   = (const float*)d_in[1];
    const float* x3   = (const float*)d_in[2];
    const float* posw = (const float*)d_in[3];
    const float* lw   = (const float*)d_in[4];
    const float* lb   = (const float*)d_in[5];
    float* out = (float*)d_out;

    // ws layout: pw | pkv | pksum | kmean | kvbT(ushort)  (~21.6 MB)
    const size_t pw_sz = (size_t)NN * CC;                   // 1M floats
    float* pwb   = (float*)d_ws;
    float* pkv   = pwb + pw_sz;                             // 16*NCH * 8192
    float* pksum = pkv + (size_t)16 * NCH * 8192;           // 16*NCH * 256
    float* kmean = pksum + (size_t)16 * NCH * 256;          // 16 * 256
    unsigned short* kvbT = (unsigned short*)(kmean + (size_t)16 * 256);  // 16*8192

    k0_pw<<<1024, 256, 0, stream>>>(posw, pwb);
    k1_partial<<<BB * NHEAD * NCH / 2, 128, 0, stream>>>(x2, x3, pwb, pkv, pksum);
    k2_reduce<<<512, 256, 0, stream>>>(pkv, pksum, kvbT, kmean);
    k3_out<<<BB * 256, 256, 0, stream>>>(x1, x3, pwb, kvbT, kmean, lw, lb, out);
}